// Round 7
// baseline (1723.348 us; speedup 1.0000x reference)
//
#include <hip/hip_runtime.h>
#include <cstdint>
#include <cstddef>

#define NNODES 100000
#define NEDGES 3200000
// IN_CH=512, HID=16, LSTM_H=32, OUT_CH=40

// ---------------- helpers ----------------
static __device__ __forceinline__ float sigmoidf_(float x) {
  return 1.0f / (1.0f + __expf(-x));
}
static __device__ __forceinline__ float tanh_(float x) {
  float e = __expf(-2.0f * fabsf(x));
  float t = (1.0f - e) / (1.0f + e);
  return copysignf(t, x);
}

static __device__ __forceinline__ int edge_at(const void* ei, int is32, size_t idx) {
  return is32 ? ((const int*)ei)[idx] : (int)((const long long*)ei)[idx];
}

// ---------------- init: zero degree counts + dtype detect ----------------
__global__ void k_init(const unsigned int* __restrict__ ei, int* __restrict__ cnt,
                       int* __restrict__ flag, int n) {
  int i = blockIdx.x * blockDim.x + threadIdx.x;
  if (i < n) cnt[i] = 0;
  if (blockIdx.x == 0) {
    if (threadIdx.x == 0) flag[0] = 0;
    __syncthreads();
    unsigned v = ei[2 * threadIdx.x + 1];
    if (v != 0) atomicOr(flag, 1);  // nonzero -> data is int32
  }
}

// ---------------- degree / CSR build ----------------
__global__ void k_count(const void* __restrict__ ei, const int* __restrict__ flag,
                        int* __restrict__ cnt, int e) {
  int i = blockIdx.x * blockDim.x + threadIdx.x;
  if (i >= e) return;
  int is32 = *flag;
  int d = edge_at(ei, is32, (size_t)e + i);  // dst row
  atomicAdd(&cnt[d], 1);
}

// per-block inclusive scan over 1024 elements (256 thr x 4), + dinv fold-in
__global__ void k_scan1(const int* __restrict__ cnt, int* __restrict__ inc,
                        int* __restrict__ bsum, float* __restrict__ dinv, int n) {
  __shared__ int lds[256];
  int tid = threadIdx.x;
  int base = blockIdx.x * 1024 + tid * 4;
  int v0 = 0, v1 = 0, v2 = 0, v3 = 0;
  if (base + 0 < n) v0 = cnt[base + 0];
  if (base + 1 < n) v1 = cnt[base + 1];
  if (base + 2 < n) v2 = cnt[base + 2];
  if (base + 3 < n) v3 = cnt[base + 3];
  if (base + 0 < n) dinv[base + 0] = rsqrtf((float)v0 + 1.0f);
  if (base + 1 < n) dinv[base + 1] = rsqrtf((float)v1 + 1.0f);
  if (base + 2 < n) dinv[base + 2] = rsqrtf((float)v2 + 1.0f);
  if (base + 3 < n) dinv[base + 3] = rsqrtf((float)v3 + 1.0f);
  int s = v0 + v1 + v2 + v3;
  lds[tid] = s;
  __syncthreads();
  for (int off = 1; off < 256; off <<= 1) {
    int t = (tid >= off) ? lds[tid - off] : 0;
    __syncthreads();
    lds[tid] += t;
    __syncthreads();
  }
  int excl = lds[tid] - s;
  int r0 = excl + v0, r1 = r0 + v1, r2 = r1 + v2, r3 = r2 + v3;
  if (base + 0 < n) inc[base + 0] = r0;
  if (base + 1 < n) inc[base + 1] = r1;
  if (base + 2 < n) inc[base + 2] = r2;
  if (base + 3 < n) inc[base + 3] = r3;
  if (tid == 255) bsum[blockIdx.x] = lds[255];
}

// single-block exclusive scan of block sums (nb <= 128)
__global__ void k_scan2(const int* __restrict__ bsum, int* __restrict__ boff, int nb) {
  __shared__ int lds[128];
  int tid = threadIdx.x;
  int v = (tid < nb) ? bsum[tid] : 0;
  lds[tid] = v;
  __syncthreads();
  for (int off = 1; off < 128; off <<= 1) {
    int t = (tid >= off) ? lds[tid - off] : 0;
    __syncthreads();
    lds[tid] += t;
    __syncthreads();
  }
  if (tid < nb) boff[tid] = lds[tid] - v;
}

__global__ void k_scan3(const int* __restrict__ inc, const int* __restrict__ boff,
                        int* __restrict__ rowoff, int* __restrict__ cursor, int n) {
  int i = blockIdx.x * blockDim.x + threadIdx.x;
  if (i >= n) return;
  rowoff[i + 1] = inc[i] + boff[i >> 10];
  int prev = (i == 0) ? 0 : inc[i - 1] + boff[(i - 1) >> 10];
  if (i == 0) rowoff[0] = 0;
  cursor[i] = prev;
}

__global__ void k_fill(const void* __restrict__ ei, const int* __restrict__ flag,
                       int* __restrict__ cursor, int* __restrict__ col, int e) {
  int i = blockIdx.x * blockDim.x + threadIdx.x;
  if (i >= e) return;
  int is32 = *flag;
  int s = edge_at(ei, is32, (size_t)i);
  int d = edge_at(ei, is32, (size_t)e + i);
  int pos = atomicAdd(&cursor[d], 1);
  col[pos] = s;
}

// ---------------- fold-reduction: 16 partials over 64 lanes -> 17 shuffles --
static __device__ __forceinline__ int foldj(int lane) {
  return ((lane >> 5) & 1) * 8 + ((lane >> 4) & 1) * 4 +
         ((lane >> 3) & 1) * 2 + ((lane >> 2) & 1);
}

static __device__ __forceinline__ float fold16(float (&a)[16], int lane) {
  bool h5 = (lane & 32) != 0;
#pragma unroll
  for (int jj = 0; jj < 8; ++jj) {
    float send = h5 ? a[jj] : a[jj + 8];
    float recv = __shfl_xor(send, 32);
    float mine = h5 ? a[jj + 8] : a[jj];
    a[jj] = mine + recv;
  }
  bool h4 = (lane & 16) != 0;
#pragma unroll
  for (int jj = 0; jj < 4; ++jj) {
    float send = h4 ? a[jj] : a[jj + 4];
    float recv = __shfl_xor(send, 16);
    float mine = h4 ? a[jj + 4] : a[jj];
    a[jj] = mine + recv;
  }
  bool h3 = (lane & 8) != 0;
#pragma unroll
  for (int jj = 0; jj < 2; ++jj) {
    float send = h3 ? a[jj] : a[jj + 2];
    float recv = __shfl_xor(send, 8);
    float mine = h3 ? a[jj + 2] : a[jj];
    a[jj] = mine + recv;
  }
  bool h2 = (lane & 4) != 0;
  {
    float send = h2 ? a[0] : a[1];
    float recv = __shfl_xor(send, 4);
    float mine = h2 ? a[1] : a[0];
    a[0] = mine + recv;
  }
  a[0] += __shfl_xor(a[0], 1);
  a[0] += __shfl_xor(a[0], 2);
  return a[0];
}

// ---------------- GEMM1: h0' = dinv * (x @ W1) ----------------
__global__ __launch_bounds__(256) void k_gemm1(const float* __restrict__ x,
                                               const float* __restrict__ W1,
                                               const float* __restrict__ dinv,
                                               float* __restrict__ h0p, int n) {
  __shared__ __align__(16) float w1t[16 * 516];
  int tid = threadIdx.x;
  for (int i = tid; i < 512 * 16; i += 256) w1t[(i & 15) * 516 + (i >> 4)] = W1[i];
  __syncthreads();
  int lane = tid & 63;
  int wid = tid >> 6;
  int jme = foldj(lane);
  bool w0 = (lane & 3) == 0;
  for (int n0 = (blockIdx.x * 4 + wid) * 4; n0 < n; n0 += gridDim.x * 16) {
    float acc[4][16];
#pragma unroll
    for (int m = 0; m < 4; ++m)
#pragma unroll
      for (int j = 0; j < 16; ++j) acc[m][j] = 0.f;
#pragma unroll
    for (int t = 0; t < 2; ++t) {
      int k0 = t * 256 + lane * 4;
      float4 xv[4];
#pragma unroll
      for (int m = 0; m < 4; ++m) {
        int node = n0 + m;
        xv[m] = (node < n)
                    ? *reinterpret_cast<const float4*>(x + (size_t)node * 512 + k0)
                    : make_float4(0.f, 0.f, 0.f, 0.f);
      }
#pragma unroll
      for (int j = 0; j < 16; ++j) {
        float4 wv = *reinterpret_cast<const float4*>(&w1t[j * 516 + k0]);
#pragma unroll
        for (int m = 0; m < 4; ++m) {
          acc[m][j] = fmaf(xv[m].x, wv.x, acc[m][j]);
          acc[m][j] = fmaf(xv[m].y, wv.y, acc[m][j]);
          acc[m][j] = fmaf(xv[m].z, wv.z, acc[m][j]);
          acc[m][j] = fmaf(xv[m].w, wv.w, acc[m][j]);
        }
      }
    }
#pragma unroll
    for (int m = 0; m < 4; ++m) {
      float r = fold16(acc[m], lane);
      int node = n0 + m;
      if (w0 && node < n) h0p[(size_t)node * 16 + jme] = r * dinv[node];
    }
  }
}

// ---------------- agg1 (+fused gemm2) ----------------
__global__ __launch_bounds__(256) void k_agg1(const float* __restrict__ hin,
                                              const int* __restrict__ rowoff,
                                              const int* __restrict__ col,
                                              const float* __restrict__ dinv,
                                              const float* __restrict__ b1,
                                              const float* __restrict__ W2,
                                              float* __restrict__ x1out,
                                              float* __restrict__ t2out, int n) {
  __shared__ float w2s[256];
  __shared__ float bs[16];
  int tid = threadIdx.x;
  if (tid < 256) w2s[tid] = W2[tid];
  if (tid < 16) bs[tid] = b1[tid];
  __syncthreads();
  int gid = blockIdx.x * 256 + tid;
  int v = gid >> 2;
  if (v >= n) return;
  int g = gid & 3, c4 = g * 4;
  int e0 = rowoff[v], e1 = rowoff[v + 1];
  float4 s = *reinterpret_cast<const float4*>(hin + (size_t)v * 16 + c4);  // self
  for (int e = e0; e < e1; ++e) {
    int u = col[e];
    float4 hv = *reinterpret_cast<const float4*>(hin + (size_t)u * 16 + c4);
    s.x += hv.x; s.y += hv.y; s.z += hv.z; s.w += hv.w;
  }
  float dv = dinv[v];
  float4 r;
  r.x = fmaxf(fmaf(dv, s.x, bs[c4 + 0]), 0.f);
  r.y = fmaxf(fmaf(dv, s.y, bs[c4 + 1]), 0.f);
  r.z = fmaxf(fmaf(dv, s.z, bs[c4 + 2]), 0.f);
  r.w = fmaxf(fmaf(dv, s.w, bs[c4 + 3]), 0.f);
  *reinterpret_cast<float4*>(x1out + (size_t)v * 16 + c4) = r;
  // fused gemm2: gather full x1 row via quad shuffles
  float xk[16];
#pragma unroll
  for (int g2 = 0; g2 < 4; ++g2) {
    xk[g2 * 4 + 0] = __shfl(r.x, g2, 4);
    xk[g2 * 4 + 1] = __shfl(r.y, g2, 4);
    xk[g2 * 4 + 2] = __shfl(r.z, g2, 4);
    xk[g2 * 4 + 3] = __shfl(r.w, g2, 4);
  }
  float4 t = make_float4(0.f, 0.f, 0.f, 0.f);
#pragma unroll
  for (int k = 0; k < 16; ++k) {
    t.x = fmaf(xk[k], w2s[k * 16 + c4 + 0], t.x);
    t.y = fmaf(xk[k], w2s[k * 16 + c4 + 1], t.y);
    t.z = fmaf(xk[k], w2s[k * 16 + c4 + 2], t.z);
    t.w = fmaf(xk[k], w2s[k * 16 + c4 + 3], t.w);
  }
  t.x *= dv; t.y *= dv; t.z *= dv; t.w *= dv;
  *reinterpret_cast<float4*>(t2out + (size_t)v * 16 + c4) = t;
}

// ---------------- agg2 ----------------
__global__ __launch_bounds__(256) void k_agg2(const float* __restrict__ hin,
                                              const int* __restrict__ rowoff,
                                              const int* __restrict__ col,
                                              const float* __restrict__ dinv,
                                              const float* __restrict__ b2,
                                              float* __restrict__ hout, int n) {
  __shared__ float bs[16];
  int tid = threadIdx.x;
  if (tid < 16) bs[tid] = b2[tid];
  __syncthreads();
  int gid = blockIdx.x * 256 + tid;
  int v = gid >> 2;
  if (v >= n) return;
  int c4 = (gid & 3) * 4;
  int e0 = rowoff[v], e1 = rowoff[v + 1];
  float4 s = *reinterpret_cast<const float4*>(hin + (size_t)v * 16 + c4);
  for (int e = e0; e < e1; ++e) {
    int u = col[e];
    float4 hv = *reinterpret_cast<const float4*>(hin + (size_t)u * 16 + c4);
    s.x += hv.x; s.y += hv.y; s.z += hv.z; s.w += hv.w;
  }
  float dv = dinv[v];
  float4 r;
  r.x = fmaxf(fmaf(dv, s.x, bs[c4 + 0]), 0.f);
  r.y = fmaxf(fmaf(dv, s.y, bs[c4 + 1]), 0.f);
  r.z = fmaxf(fmaf(dv, s.z, bs[c4 + 2]), 0.f);
  r.w = fmaxf(fmaf(dv, s.w, bs[c4 + 3]), 0.f);
  *reinterpret_cast<float4*>(hout + (size_t)v * 16 + c4) = r;
}

// ---------------- fused bidirectional LSTM + attention, float2 x 4 nodes ----
// Wave = 4 nodes: lanes 0-31 hold nodes (n0,n0+1) packed float2, lanes 32-63
// the next pair. Lane j owns hidden unit j.
// SEQUENTIAL cells, one accumulator set live at a time (round-6 pairing
// needed >128 VGPR -> cap forced 1.2 GB/dispatch scratch traffic).
template <bool FIRST>
static __device__ __forceinline__ void cell2(float2 xv, float2& h, float2& c,
                                             const float4* __restrict__ wT,
                                             const float4* __restrict__ b4, int j) {
  float4 ax = b4[j];
  float4 ay = ax;
#pragma unroll
  for (int k = 0; k < 16; ++k) {
    float kx = __shfl(xv.x, k, 32);
    float ky = __shfl(xv.y, k, 32);
    float4 w = wT[k * 32 + j];
    ax.x = fmaf(kx, w.x, ax.x); ax.y = fmaf(kx, w.y, ax.y);
    ax.z = fmaf(kx, w.z, ax.z); ax.w = fmaf(kx, w.w, ax.w);
    ay.x = fmaf(ky, w.x, ay.x); ay.y = fmaf(ky, w.y, ay.y);
    ay.z = fmaf(ky, w.z, ay.z); ay.w = fmaf(ky, w.w, ay.w);
  }
  if (!FIRST) {
#pragma unroll
    for (int k = 0; k < 32; ++k) {
      float hx = __shfl(h.x, k, 32);
      float hy = __shfl(h.y, k, 32);
      float4 w = wT[(16 + k) * 32 + j];
      ax.x = fmaf(hx, w.x, ax.x); ax.y = fmaf(hx, w.y, ax.y);
      ax.z = fmaf(hx, w.z, ax.z); ax.w = fmaf(hx, w.w, ax.w);
      ay.x = fmaf(hy, w.x, ay.x); ay.y = fmaf(hy, w.y, ay.y);
      ay.z = fmaf(hy, w.z, ay.z); ay.w = fmaf(hy, w.w, ay.w);
    }
  }
  float ix = sigmoidf_(ax.x), iy = sigmoidf_(ay.x);
  float gx = tanh_(ax.z),     gy = tanh_(ay.z);
  float ox = sigmoidf_(ax.w), oy = sigmoidf_(ay.w);
  if (FIRST) {
    c.x = ix * gx;
    c.y = iy * gy;
  } else {
    float fx = sigmoidf_(ax.y), fy = sigmoidf_(ay.y);
    c.x = fmaf(fx, c.x, ix * gx);
    c.y = fmaf(fy, c.y, iy * gy);
  }
  h.x = ox * tanh_(c.x);
  h.y = oy * tanh_(c.y);
}

// __launch_bounds__(256,3): 12 waves/CU (= the LDS limit: 3 blocks x 50.7KB),
// VGPR ceiling ~170 — room for the natural ~100-130 allocation, no spill.
__global__ __launch_bounds__(256, 3) void k_lstm(
    const float* __restrict__ x1g, const float* __restrict__ x2g,
    const float* __restrict__ wihf, const float* __restrict__ whhf,
    const float* __restrict__ bfp,
    const float* __restrict__ wihb, const float* __restrict__ whhb,
    const float* __restrict__ bbp,
    const float* __restrict__ attw, const float* __restrict__ dinv,
    float* __restrict__ hjkp, int n) {
  __shared__ float4 wf[48 * 32];
  __shared__ float4 wb[48 * 32];
  __shared__ float4 b4f[32];
  __shared__ float4 b4b[32];
  __shared__ float aw[64];
  int tid = threadIdx.x;
  for (int i = tid; i < 1536; i += 256) {
    int k = i >> 5, j = i & 31;
    float4 w, w2;
    if (k < 16) {
      w = make_float4(wihf[j * 16 + k], wihf[(32 + j) * 16 + k],
                      wihf[(64 + j) * 16 + k], wihf[(96 + j) * 16 + k]);
      w2 = make_float4(wihb[j * 16 + k], wihb[(32 + j) * 16 + k],
                       wihb[(64 + j) * 16 + k], wihb[(96 + j) * 16 + k]);
    } else {
      int kk = k - 16;
      w = make_float4(whhf[j * 32 + kk], whhf[(32 + j) * 32 + kk],
                      whhf[(64 + j) * 32 + kk], whhf[(96 + j) * 32 + kk]);
      w2 = make_float4(whhb[j * 32 + kk], whhb[(32 + j) * 32 + kk],
                       whhb[(64 + j) * 32 + kk], whhb[(96 + j) * 32 + kk]);
    }
    wf[i] = w;
    wb[i] = w2;
  }
  if (tid < 32) {
    b4f[tid] = make_float4(bfp[tid], bfp[32 + tid], bfp[64 + tid], bfp[96 + tid]);
    b4b[tid] = make_float4(bbp[tid], bbp[32 + tid], bbp[64 + tid], bbp[96 + tid]);
  }
  if (tid < 64) aw[tid] = attw[tid];
  __syncthreads();

  int j = tid & 31;
  float awf = aw[j];
  float awb2 = aw[32 + j];

  for (int base = blockIdx.x * 16; base < n; base += gridDim.x * 16) {
    int n0 = base + (tid >> 5) * 2;  // this 32-group's node pair
    bool v0 = n0 < n, v1 = (n0 + 1) < n;
    float2 x0 = make_float2(0.f, 0.f), x1v = make_float2(0.f, 0.f);
    if (j < 16) {
      if (v0) { x0.x = x1g[(size_t)n0 * 16 + j]; x1v.x = x2g[(size_t)n0 * 16 + j]; }
      if (v1) { x0.y = x1g[(size_t)(n0 + 1) * 16 + j]; x1v.y = x2g[(size_t)(n0 + 1) * 16 + j]; }
    }
    float2 h = make_float2(0.f, 0.f), c = make_float2(0.f, 0.f);
    float2 s0, s1;
    // forward over [x1, x2]
    cell2<true>(x0, h, c, wf, b4f, j);   // hf0
    s0.x = h.x * awf; s0.y = h.y * awf;
    cell2<false>(x1v, h, c, wf, b4f, j); // hf1
    s1.x = h.x * awf; s1.y = h.y * awf;
    // backward over [x2, x1]
    h = make_float2(0.f, 0.f); c = make_float2(0.f, 0.f);
    cell2<true>(x1v, h, c, wb, b4b, j);  // hb1
    s1.x = fmaf(h.x, awb2, s1.x); s1.y = fmaf(h.y, awb2, s1.y);
    cell2<false>(x0, h, c, wb, b4b, j);  // hb0
    s0.x = fmaf(h.x, awb2, s0.x); s0.y = fmaf(h.y, awb2, s0.y);
    // reduce scores within the 32-lane group (att_b cancels in softmax)
#pragma unroll
    for (int mm = 16; mm >= 1; mm >>= 1) {
      s0.x += __shfl_xor(s0.x, mm, 32); s0.y += __shfl_xor(s0.y, mm, 32);
      s1.x += __shfl_xor(s1.x, mm, 32); s1.y += __shfl_xor(s1.y, mm, 32);
    }
    float mxx = fmaxf(s0.x, s1.x), mxy = fmaxf(s0.y, s1.y);
    float e0x = __expf(s0.x - mxx), e1x = __expf(s1.x - mxx);
    float e0y = __expf(s0.y - mxy), e1y = __expf(s1.y - mxy);
    float ivx = 1.0f / (e0x + e1x), ivy = 1.0f / (e0y + e1y);
    if (j < 16) {
      if (v0) hjkp[(size_t)n0 * 16 + j] =
          dinv[n0] * (e0x * ivx * x0.x + e1x * ivx * x1v.x);
      if (v1) hjkp[(size_t)(n0 + 1) * 16 + j] =
          dinv[n0 + 1] * (e0y * ivy * x0.y + e1y * ivy * x1v.y);
    }
  }
}

// ---------------- agg3 (+fused final linear + log_softmax) ------------------
__global__ __launch_bounds__(256) void k_agg_out(const float* __restrict__ hin,
                                                 const int* __restrict__ rowoff,
                                                 const int* __restrict__ col,
                                                 const float* __restrict__ dinv,
                                                 const float* __restrict__ linw,
                                                 const float* __restrict__ linb,
                                                 float* __restrict__ out, int n) {
  __shared__ float lw[640];
  __shared__ float lb[40];
  int tid = threadIdx.x;
  for (int i = tid; i < 640; i += 256) lw[i] = linw[i];
  if (tid < 40) lb[tid] = linb[tid];
  __syncthreads();
  int gid = blockIdx.x * 256 + tid;
  int v = gid >> 2;
  if (v >= n) return;
  int g = gid & 3, c4 = g * 4;
  int e0 = rowoff[v], e1 = rowoff[v + 1];
  float4 s = *reinterpret_cast<const float4*>(hin + (size_t)v * 16 + c4);
  for (int e = e0; e < e1; ++e) {
    int u = col[e];
    float4 hv = *reinterpret_cast<const float4*>(hin + (size_t)u * 16 + c4);
    s.x += hv.x; s.y += hv.y; s.z += hv.z; s.w += hv.w;
  }
  float dv = dinv[v];
  float4 r = make_float4(dv * s.x, dv * s.y, dv * s.z, dv * s.w);
  float hk[16];
#pragma unroll
  for (int g2 = 0; g2 < 4; ++g2) {
    hk[g2 * 4 + 0] = __shfl(r.x, g2, 4);
    hk[g2 * 4 + 1] = __shfl(r.y, g2, 4);
    hk[g2 * 4 + 2] = __shfl(r.z, g2, 4);
    hk[g2 * 4 + 3] = __shfl(r.w, g2, 4);
  }
  int ob = g * 10;  // this lane's 10 output channels
  float lg[10];
#pragma unroll
  for (int t = 0; t < 10; ++t) lg[t] = lb[ob + t];
#pragma unroll
  for (int k = 0; k < 16; ++k) {
#pragma unroll
    for (int t = 0; t < 10; ++t) lg[t] = fmaf(hk[k], lw[k * 40 + ob + t], lg[t]);
  }
  float m = lg[0];
#pragma unroll
  for (int t = 1; t < 10; ++t) m = fmaxf(m, lg[t]);
  m = fmaxf(m, __shfl_xor(m, 1, 4));
  m = fmaxf(m, __shfl_xor(m, 2, 4));
  float se = 0.f;
#pragma unroll
  for (int t = 0; t < 10; ++t) se += __expf(lg[t] - m);
  se += __shfl_xor(se, 1, 4);
  se += __shfl_xor(se, 2, 4);
  float ls = __logf(se) + m;
#pragma unroll
  for (int t = 0; t < 10; ++t) out[(size_t)v * 40 + ob + t] = lg[t] - ls;
}

// ---------------- launcher ----------------
extern "C" void kernel_launch(void* const* d_in, const int* in_sizes, int n_in,
                              void* d_out, int out_size, void* d_ws, size_t ws_size,
                              hipStream_t stream) {
  (void)in_sizes; (void)n_in; (void)out_size; (void)ws_size;
  const float* x    = (const float*)d_in[0];
  const void*  ei   = d_in[1];
  const float* W1   = (const float*)d_in[2];
  const float* b1   = (const float*)d_in[3];
  const float* W2   = (const float*)d_in[4];
  const float* b2   = (const float*)d_in[5];
  const float* wihf = (const float*)d_in[6];
  const float* whhf = (const float*)d_in[7];
  const float* bfp  = (const float*)d_in[8];
  const float* wihb = (const float*)d_in[9];
  const float* whhb = (const float*)d_in[10];
  const float* bbp  = (const float*)d_in[11];
  const float* attw = (const float*)d_in[12];
  // d_in[13] = att_b: cancels exactly in the 2-way softmax -> unused
  const float* linw = (const float*)d_in[14];
  const float* linb = (const float*)d_in[15];
  float* out = (float*)d_out;

  char* w = (char*)d_ws;
  size_t off = 0;
  auto alloc = [&](size_t bytes) -> void* {
    void* p = w + off;
    off += (bytes + 255) & ~(size_t)255;
    return p;
  };
  int*   cnt    = (int*)alloc((size_t)NNODES * 4);
  float* dinv   = (float*)alloc((size_t)NNODES * 4);
  int*   rowoff = (int*)alloc((size_t)(NNODES + 1) * 4);
  int*   cursor = (int*)alloc((size_t)NNODES * 4);
  int*   bsum   = (int*)alloc(256 * 4);
  int*   boff   = (int*)alloc(256 * 4);
  int*   incb   = (int*)alloc((size_t)NNODES * 4);
  int*   flag   = (int*)alloc(256);
  int*   colv   = (int*)alloc((size_t)NEDGES * 4);
  float* bufA   = (float*)alloc((size_t)NNODES * 16 * 4);  // h0' / x2
  float* bufB   = (float*)alloc((size_t)NNODES * 16 * 4);  // x1
  float* bufC   = (float*)alloc((size_t)NNODES * 16 * 4);  // t2' / hjk'

  const int TPB = 256;
  const int gN  = (NNODES + TPB - 1) / TPB;        // 391
  const int gE  = (NEDGES + TPB - 1) / TPB;        // 12500
  const int nb1 = (NNODES + 1023) / 1024;          // 98
  const int gA  = (NNODES * 4 + TPB - 1) / TPB;    // 1563

  k_init<<<gN, TPB, 0, stream>>>((const unsigned int*)ei, cnt, flag, NNODES);
  k_count<<<gE, TPB, 0, stream>>>(ei, flag, cnt, NEDGES);
  k_scan1<<<nb1, 256, 0, stream>>>(cnt, incb, bsum, dinv, NNODES);
  k_scan2<<<1, 128, 0, stream>>>(bsum, boff, nb1);
  k_scan3<<<gN, TPB, 0, stream>>>(incb, boff, rowoff, cursor, NNODES);
  k_fill<<<gE, TPB, 0, stream>>>(ei, flag, cursor, colv, NEDGES);

  k_gemm1<<<1024, 256, 0, stream>>>(x, W1, dinv, bufA, NNODES);
  k_agg1<<<gA, TPB, 0, stream>>>(bufA, rowoff, colv, dinv, b1, W2, bufB, bufC,
                                 NNODES);                       // x1, t2'
  k_agg2<<<gA, TPB, 0, stream>>>(bufC, rowoff, colv, dinv, b2, bufA, NNODES); // x2
  k_lstm<<<1024, 256, 0, stream>>>(bufB, bufA, wihf, whhf, bfp, wihb, whhb, bbp,
                                   attw, dinv, bufC, NNODES);   // hjk'
  k_agg_out<<<gA, TPB, 0, stream>>>(bufC, rowoff, colv, dinv, linw, linb, out,
                                    NNODES);
}

// Round 8
// 1091.753 us; speedup vs baseline: 1.5785x; 1.5785x over previous
//
#include <hip/hip_runtime.h>
#include <cstdint>
#include <cstddef>

#define NNODES 100000
#define NEDGES 3200000
// IN_CH=512, HID=16, LSTM_H=32, OUT_CH=40

// ---------------- helpers ----------------
static __device__ __forceinline__ float sigmoidf_(float x) {
  return 1.0f / (1.0f + __expf(-x));
}
static __device__ __forceinline__ float tanh_(float x) {
  float e = __expf(-2.0f * fabsf(x));
  float t = (1.0f - e) / (1.0f + e);
  return copysignf(t, x);
}

static __device__ __forceinline__ int edge_at(const void* ei, int is32, size_t idx) {
  return is32 ? ((const int*)ei)[idx] : (int)((const long long*)ei)[idx];
}

// ---------------- init: zero degree counts + dtype detect ----------------
__global__ void k_init(const unsigned int* __restrict__ ei, int* __restrict__ cnt,
                       int* __restrict__ flag, int n) {
  int i = blockIdx.x * blockDim.x + threadIdx.x;
  if (i < n) cnt[i] = 0;
  if (blockIdx.x == 0) {
    if (threadIdx.x == 0) flag[0] = 0;
    __syncthreads();
    unsigned v = ei[2 * threadIdx.x + 1];
    if (v != 0) atomicOr(flag, 1);  // nonzero -> data is int32
  }
}

// ---------------- degree / CSR build ----------------
__global__ void k_count(const void* __restrict__ ei, const int* __restrict__ flag,
                        int* __restrict__ cnt, int e) {
  int i = blockIdx.x * blockDim.x + threadIdx.x;
  if (i >= e) return;
  int is32 = *flag;
  int d = edge_at(ei, is32, (size_t)e + i);  // dst row
  atomicAdd(&cnt[d], 1);
}

// per-block inclusive scan over 1024 elements (256 thr x 4), + dinv fold-in
__global__ void k_scan1(const int* __restrict__ cnt, int* __restrict__ inc,
                        int* __restrict__ bsum, float* __restrict__ dinv, int n) {
  __shared__ int lds[256];
  int tid = threadIdx.x;
  int base = blockIdx.x * 1024 + tid * 4;
  int v0 = 0, v1 = 0, v2 = 0, v3 = 0;
  if (base + 0 < n) v0 = cnt[base + 0];
  if (base + 1 < n) v1 = cnt[base + 1];
  if (base + 2 < n) v2 = cnt[base + 2];
  if (base + 3 < n) v3 = cnt[base + 3];
  if (base + 0 < n) dinv[base + 0] = rsqrtf((float)v0 + 1.0f);
  if (base + 1 < n) dinv[base + 1] = rsqrtf((float)v1 + 1.0f);
  if (base + 2 < n) dinv[base + 2] = rsqrtf((float)v2 + 1.0f);
  if (base + 3 < n) dinv[base + 3] = rsqrtf((float)v3 + 1.0f);
  int s = v0 + v1 + v2 + v3;
  lds[tid] = s;
  __syncthreads();
  for (int off = 1; off < 256; off <<= 1) {
    int t = (tid >= off) ? lds[tid - off] : 0;
    __syncthreads();
    lds[tid] += t;
    __syncthreads();
  }
  int excl = lds[tid] - s;
  int r0 = excl + v0, r1 = r0 + v1, r2 = r1 + v2, r3 = r2 + v3;
  if (base + 0 < n) inc[base + 0] = r0;
  if (base + 1 < n) inc[base + 1] = r1;
  if (base + 2 < n) inc[base + 2] = r2;
  if (base + 3 < n) inc[base + 3] = r3;
  if (tid == 255) bsum[blockIdx.x] = lds[255];
}

// single-block exclusive scan of block sums (nb <= 128)
__global__ void k_scan2(const int* __restrict__ bsum, int* __restrict__ boff, int nb) {
  __shared__ int lds[128];
  int tid = threadIdx.x;
  int v = (tid < nb) ? bsum[tid] : 0;
  lds[tid] = v;
  __syncthreads();
  for (int off = 1; off < 128; off <<= 1) {
    int t = (tid >= off) ? lds[tid - off] : 0;
    __syncthreads();
    lds[tid] += t;
    __syncthreads();
  }
  if (tid < nb) boff[tid] = lds[tid] - v;
}

__global__ void k_scan3(const int* __restrict__ inc, const int* __restrict__ boff,
                        int* __restrict__ rowoff, int* __restrict__ cursor, int n) {
  int i = blockIdx.x * blockDim.x + threadIdx.x;
  if (i >= n) return;
  rowoff[i + 1] = inc[i] + boff[i >> 10];
  int prev = (i == 0) ? 0 : inc[i - 1] + boff[(i - 1) >> 10];
  if (i == 0) rowoff[0] = 0;
  cursor[i] = prev;
}

__global__ void k_fill(const void* __restrict__ ei, const int* __restrict__ flag,
                       int* __restrict__ cursor, int* __restrict__ col, int e) {
  int i = blockIdx.x * blockDim.x + threadIdx.x;
  if (i >= e) return;
  int is32 = *flag;
  int s = edge_at(ei, is32, (size_t)i);
  int d = edge_at(ei, is32, (size_t)e + i);
  int pos = atomicAdd(&cursor[d], 1);
  col[pos] = s;
}

// ---------------- fold-reduction: 16 partials over 64 lanes -> 17 shuffles --
static __device__ __forceinline__ int foldj(int lane) {
  return ((lane >> 5) & 1) * 8 + ((lane >> 4) & 1) * 4 +
         ((lane >> 3) & 1) * 2 + ((lane >> 2) & 1);
}

static __device__ __forceinline__ float fold16(float (&a)[16], int lane) {
  bool h5 = (lane & 32) != 0;
#pragma unroll
  for (int jj = 0; jj < 8; ++jj) {
    float send = h5 ? a[jj] : a[jj + 8];
    float recv = __shfl_xor(send, 32);
    float mine = h5 ? a[jj + 8] : a[jj];
    a[jj] = mine + recv;
  }
  bool h4 = (lane & 16) != 0;
#pragma unroll
  for (int jj = 0; jj < 4; ++jj) {
    float send = h4 ? a[jj] : a[jj + 4];
    float recv = __shfl_xor(send, 16);
    float mine = h4 ? a[jj + 4] : a[jj];
    a[jj] = mine + recv;
  }
  bool h3 = (lane & 8) != 0;
#pragma unroll
  for (int jj = 0; jj < 2; ++jj) {
    float send = h3 ? a[jj] : a[jj + 2];
    float recv = __shfl_xor(send, 8);
    float mine = h3 ? a[jj + 2] : a[jj];
    a[jj] = mine + recv;
  }
  bool h2 = (lane & 4) != 0;
  {
    float send = h2 ? a[0] : a[1];
    float recv = __shfl_xor(send, 4);
    float mine = h2 ? a[1] : a[0];
    a[0] = mine + recv;
  }
  a[0] += __shfl_xor(a[0], 1);
  a[0] += __shfl_xor(a[0], 2);
  return a[0];
}

// ---------------- GEMM1: h0' = dinv * (x @ W1) ----------------
__global__ __launch_bounds__(256) void k_gemm1(const float* __restrict__ x,
                                               const float* __restrict__ W1,
                                               const float* __restrict__ dinv,
                                               float* __restrict__ h0p, int n) {
  __shared__ __align__(16) float w1t[16 * 516];
  int tid = threadIdx.x;
  for (int i = tid; i < 512 * 16; i += 256) w1t[(i & 15) * 516 + (i >> 4)] = W1[i];
  __syncthreads();
  int lane = tid & 63;
  int wid = tid >> 6;
  int jme = foldj(lane);
  bool w0 = (lane & 3) == 0;
  for (int n0 = (blockIdx.x * 4 + wid) * 4; n0 < n; n0 += gridDim.x * 16) {
    float acc[4][16];
#pragma unroll
    for (int m = 0; m < 4; ++m)
#pragma unroll
      for (int j = 0; j < 16; ++j) acc[m][j] = 0.f;
#pragma unroll
    for (int t = 0; t < 2; ++t) {
      int k0 = t * 256 + lane * 4;
      float4 xv[4];
#pragma unroll
      for (int m = 0; m < 4; ++m) {
        int node = n0 + m;
        xv[m] = (node < n)
                    ? *reinterpret_cast<const float4*>(x + (size_t)node * 512 + k0)
                    : make_float4(0.f, 0.f, 0.f, 0.f);
      }
#pragma unroll
      for (int j = 0; j < 16; ++j) {
        float4 wv = *reinterpret_cast<const float4*>(&w1t[j * 516 + k0]);
#pragma unroll
        for (int m = 0; m < 4; ++m) {
          acc[m][j] = fmaf(xv[m].x, wv.x, acc[m][j]);
          acc[m][j] = fmaf(xv[m].y, wv.y, acc[m][j]);
          acc[m][j] = fmaf(xv[m].z, wv.z, acc[m][j]);
          acc[m][j] = fmaf(xv[m].w, wv.w, acc[m][j]);
        }
      }
    }
#pragma unroll
    for (int m = 0; m < 4; ++m) {
      float r = fold16(acc[m], lane);
      int node = n0 + m;
      if (w0 && node < n) h0p[(size_t)node * 16 + jme] = r * dinv[node];
    }
  }
}

// ---------------- agg1 (+fused gemm2) ----------------
__global__ __launch_bounds__(256) void k_agg1(const float* __restrict__ hin,
                                              const int* __restrict__ rowoff,
                                              const int* __restrict__ col,
                                              const float* __restrict__ dinv,
                                              const float* __restrict__ b1,
                                              const float* __restrict__ W2,
                                              float* __restrict__ x1out,
                                              float* __restrict__ t2out, int n) {
  __shared__ float w2s[256];
  __shared__ float bs[16];
  int tid = threadIdx.x;
  if (tid < 256) w2s[tid] = W2[tid];
  if (tid < 16) bs[tid] = b1[tid];
  __syncthreads();
  int gid = blockIdx.x * 256 + tid;
  int v = gid >> 2;
  if (v >= n) return;
  int g = gid & 3, c4 = g * 4;
  int e0 = rowoff[v], e1 = rowoff[v + 1];
  float4 s = *reinterpret_cast<const float4*>(hin + (size_t)v * 16 + c4);  // self
  for (int e = e0; e < e1; ++e) {
    int u = col[e];
    float4 hv = *reinterpret_cast<const float4*>(hin + (size_t)u * 16 + c4);
    s.x += hv.x; s.y += hv.y; s.z += hv.z; s.w += hv.w;
  }
  float dv = dinv[v];
  float4 r;
  r.x = fmaxf(fmaf(dv, s.x, bs[c4 + 0]), 0.f);
  r.y = fmaxf(fmaf(dv, s.y, bs[c4 + 1]), 0.f);
  r.z = fmaxf(fmaf(dv, s.z, bs[c4 + 2]), 0.f);
  r.w = fmaxf(fmaf(dv, s.w, bs[c4 + 3]), 0.f);
  *reinterpret_cast<float4*>(x1out + (size_t)v * 16 + c4) = r;
  // fused gemm2: gather full x1 row via quad shuffles
  float xk[16];
#pragma unroll
  for (int g2 = 0; g2 < 4; ++g2) {
    xk[g2 * 4 + 0] = __shfl(r.x, g2, 4);
    xk[g2 * 4 + 1] = __shfl(r.y, g2, 4);
    xk[g2 * 4 + 2] = __shfl(r.z, g2, 4);
    xk[g2 * 4 + 3] = __shfl(r.w, g2, 4);
  }
  float4 t = make_float4(0.f, 0.f, 0.f, 0.f);
#pragma unroll
  for (int k = 0; k < 16; ++k) {
    t.x = fmaf(xk[k], w2s[k * 16 + c4 + 0], t.x);
    t.y = fmaf(xk[k], w2s[k * 16 + c4 + 1], t.y);
    t.z = fmaf(xk[k], w2s[k * 16 + c4 + 2], t.z);
    t.w = fmaf(xk[k], w2s[k * 16 + c4 + 3], t.w);
  }
  t.x *= dv; t.y *= dv; t.z *= dv; t.w *= dv;
  *reinterpret_cast<float4*>(t2out + (size_t)v * 16 + c4) = t;
}

// ---------------- agg2 ----------------
__global__ __launch_bounds__(256) void k_agg2(const float* __restrict__ hin,
                                              const int* __restrict__ rowoff,
                                              const int* __restrict__ col,
                                              const float* __restrict__ dinv,
                                              const float* __restrict__ b2,
                                              float* __restrict__ hout, int n) {
  __shared__ float bs[16];
  int tid = threadIdx.x;
  if (tid < 16) bs[tid] = b2[tid];
  __syncthreads();
  int gid = blockIdx.x * 256 + tid;
  int v = gid >> 2;
  if (v >= n) return;
  int c4 = (gid & 3) * 4;
  int e0 = rowoff[v], e1 = rowoff[v + 1];
  float4 s = *reinterpret_cast<const float4*>(hin + (size_t)v * 16 + c4);
  for (int e = e0; e < e1; ++e) {
    int u = col[e];
    float4 hv = *reinterpret_cast<const float4*>(hin + (size_t)u * 16 + c4);
    s.x += hv.x; s.y += hv.y; s.z += hv.z; s.w += hv.w;
  }
  float dv = dinv[v];
  float4 r;
  r.x = fmaxf(fmaf(dv, s.x, bs[c4 + 0]), 0.f);
  r.y = fmaxf(fmaf(dv, s.y, bs[c4 + 1]), 0.f);
  r.z = fmaxf(fmaf(dv, s.z, bs[c4 + 2]), 0.f);
  r.w = fmaxf(fmaf(dv, s.w, bs[c4 + 3]), 0.f);
  *reinterpret_cast<float4*>(hout + (size_t)v * 16 + c4) = r;
}

// ---------------- fused bidirectional LSTM + attention, float2 x 4 nodes ----
// Wave = 4 nodes: lanes 0-31 hold nodes (n0,n0+1) packed float2, lanes 32-63
// the next pair. Lane j owns hidden unit j. Sequential cells.
// NO occupancy bound: measured r4/r6/r7 show caps force spill (256->138MB,
// 128->1.2GB, 84->2.0GB scratch); uncapped the allocator fits naturally and
// LDS (3 blocks x 50.7KB) limits occupancy anyway.
template <bool FIRST>
static __device__ __forceinline__ void cell2(float2 xv, float2& h, float2& c,
                                             const float4* __restrict__ wT,
                                             const float4* __restrict__ b4, int j) {
  float4 ax = b4[j];
  float4 ay = ax;
#pragma unroll
  for (int k = 0; k < 16; ++k) {
    float kx = __shfl(xv.x, k, 32);
    float ky = __shfl(xv.y, k, 32);
    float4 w = wT[k * 32 + j];
    ax.x = fmaf(kx, w.x, ax.x); ax.y = fmaf(kx, w.y, ax.y);
    ax.z = fmaf(kx, w.z, ax.z); ax.w = fmaf(kx, w.w, ax.w);
    ay.x = fmaf(ky, w.x, ay.x); ay.y = fmaf(ky, w.y, ay.y);
    ay.z = fmaf(ky, w.z, ay.z); ay.w = fmaf(ky, w.w, ay.w);
  }
  if (!FIRST) {
#pragma unroll
    for (int k = 0; k < 32; ++k) {
      float hx = __shfl(h.x, k, 32);
      float hy = __shfl(h.y, k, 32);
      float4 w = wT[(16 + k) * 32 + j];
      ax.x = fmaf(hx, w.x, ax.x); ax.y = fmaf(hx, w.y, ax.y);
      ax.z = fmaf(hx, w.z, ax.z); ax.w = fmaf(hx, w.w, ax.w);
      ay.x = fmaf(hy, w.x, ay.x); ay.y = fmaf(hy, w.y, ay.y);
      ay.z = fmaf(hy, w.z, ay.z); ay.w = fmaf(hy, w.w, ay.w);
    }
  }
  float ix = sigmoidf_(ax.x), iy = sigmoidf_(ay.x);
  float gx = tanh_(ax.z),     gy = tanh_(ay.z);
  float ox = sigmoidf_(ax.w), oy = sigmoidf_(ay.w);
  if (FIRST) {
    c.x = ix * gx;
    c.y = iy * gy;
  } else {
    float fx = sigmoidf_(ax.y), fy = sigmoidf_(ay.y);
    c.x = fmaf(fx, c.x, ix * gx);
    c.y = fmaf(fy, c.y, iy * gy);
  }
  h.x = ox * tanh_(c.x);
  h.y = oy * tanh_(c.y);
}

__global__ __launch_bounds__(256) void k_lstm(
    const float* __restrict__ x1g, const float* __restrict__ x2g,
    const float* __restrict__ wihf, const float* __restrict__ whhf,
    const float* __restrict__ bfp,
    const float* __restrict__ wihb, const float* __restrict__ whhb,
    const float* __restrict__ bbp,
    const float* __restrict__ attw, const float* __restrict__ dinv,
    float* __restrict__ hjkp, int n) {
  __shared__ float4 wf[48 * 32];
  __shared__ float4 wb[48 * 32];
  __shared__ float4 b4f[32];
  __shared__ float4 b4b[32];
  __shared__ float aw[64];
  int tid = threadIdx.x;
  for (int i = tid; i < 1536; i += 256) {
    int k = i >> 5, j = i & 31;
    float4 w, w2;
    if (k < 16) {
      w = make_float4(wihf[j * 16 + k], wihf[(32 + j) * 16 + k],
                      wihf[(64 + j) * 16 + k], wihf[(96 + j) * 16 + k]);
      w2 = make_float4(wihb[j * 16 + k], wihb[(32 + j) * 16 + k],
                       wihb[(64 + j) * 16 + k], wihb[(96 + j) * 16 + k]);
    } else {
      int kk = k - 16;
      w = make_float4(whhf[j * 32 + kk], whhf[(32 + j) * 32 + kk],
                      whhf[(64 + j) * 32 + kk], whhf[(96 + j) * 32 + kk]);
      w2 = make_float4(whhb[j * 32 + kk], whhb[(32 + j) * 32 + kk],
                       whhb[(64 + j) * 32 + kk], whhb[(96 + j) * 32 + kk]);
    }
    wf[i] = w;
    wb[i] = w2;
  }
  if (tid < 32) {
    b4f[tid] = make_float4(bfp[tid], bfp[32 + tid], bfp[64 + tid], bfp[96 + tid]);
    b4b[tid] = make_float4(bbp[tid], bbp[32 + tid], bbp[64 + tid], bbp[96 + tid]);
  }
  if (tid < 64) aw[tid] = attw[tid];
  __syncthreads();

  int j = tid & 31;
  float awf = aw[j];
  float awb2 = aw[32 + j];

  for (int base = blockIdx.x * 16; base < n; base += gridDim.x * 16) {
    int n0 = base + (tid >> 5) * 2;  // this 32-group's node pair
    bool v0 = n0 < n, v1 = (n0 + 1) < n;
    float2 x0 = make_float2(0.f, 0.f), x1v = make_float2(0.f, 0.f);
    if (j < 16) {
      if (v0) { x0.x = x1g[(size_t)n0 * 16 + j]; x1v.x = x2g[(size_t)n0 * 16 + j]; }
      if (v1) { x0.y = x1g[(size_t)(n0 + 1) * 16 + j]; x1v.y = x2g[(size_t)(n0 + 1) * 16 + j]; }
    }
    float2 h = make_float2(0.f, 0.f), c = make_float2(0.f, 0.f);
    float2 s0, s1;
    // forward over [x1, x2]
    cell2<true>(x0, h, c, wf, b4f, j);   // hf0
    s0.x = h.x * awf; s0.y = h.y * awf;
    cell2<false>(x1v, h, c, wf, b4f, j); // hf1
    s1.x = h.x * awf; s1.y = h.y * awf;
    // backward over [x2, x1]
    h = make_float2(0.f, 0.f); c = make_float2(0.f, 0.f);
    cell2<true>(x1v, h, c, wb, b4b, j);  // hb1
    s1.x = fmaf(h.x, awb2, s1.x); s1.y = fmaf(h.y, awb2, s1.y);
    cell2<false>(x0, h, c, wb, b4b, j);  // hb0
    s0.x = fmaf(h.x, awb2, s0.x); s0.y = fmaf(h.y, awb2, s0.y);
    // reduce scores within the 32-lane group (att_b cancels in softmax)
#pragma unroll
    for (int mm = 16; mm >= 1; mm >>= 1) {
      s0.x += __shfl_xor(s0.x, mm, 32); s0.y += __shfl_xor(s0.y, mm, 32);
      s1.x += __shfl_xor(s1.x, mm, 32); s1.y += __shfl_xor(s1.y, mm, 32);
    }
    float mxx = fmaxf(s0.x, s1.x), mxy = fmaxf(s0.y, s1.y);
    float e0x = __expf(s0.x - mxx), e1x = __expf(s1.x - mxx);
    float e0y = __expf(s0.y - mxy), e1y = __expf(s1.y - mxy);
    float ivx = 1.0f / (e0x + e1x), ivy = 1.0f / (e0y + e1y);
    if (j < 16) {
      if (v0) hjkp[(size_t)n0 * 16 + j] =
          dinv[n0] * (e0x * ivx * x0.x + e1x * ivx * x1v.x);
      if (v1) hjkp[(size_t)(n0 + 1) * 16 + j] =
          dinv[n0 + 1] * (e0y * ivy * x0.y + e1y * ivy * x1v.y);
    }
  }
}

// ---------------- agg3 (+fused final linear + log_softmax) ------------------
__global__ __launch_bounds__(256) void k_agg_out(const float* __restrict__ hin,
                                                 const int* __restrict__ rowoff,
                                                 const int* __restrict__ col,
                                                 const float* __restrict__ dinv,
                                                 const float* __restrict__ linw,
                                                 const float* __restrict__ linb,
                                                 float* __restrict__ out, int n) {
  __shared__ float lw[640];
  __shared__ float lb[40];
  int tid = threadIdx.x;
  for (int i = tid; i < 640; i += 256) lw[i] = linw[i];
  if (tid < 40) lb[tid] = linb[tid];
  __syncthreads();
  int gid = blockIdx.x * 256 + tid;
  int v = gid >> 2;
  if (v >= n) return;
  int g = gid & 3, c4 = g * 4;
  int e0 = rowoff[v], e1 = rowoff[v + 1];
  float4 s = *reinterpret_cast<const float4*>(hin + (size_t)v * 16 + c4);
  for (int e = e0; e < e1; ++e) {
    int u = col[e];
    float4 hv = *reinterpret_cast<const float4*>(hin + (size_t)u * 16 + c4);
    s.x += hv.x; s.y += hv.y; s.z += hv.z; s.w += hv.w;
  }
  float dv = dinv[v];
  float4 r = make_float4(dv * s.x, dv * s.y, dv * s.z, dv * s.w);
  float hk[16];
#pragma unroll
  for (int g2 = 0; g2 < 4; ++g2) {
    hk[g2 * 4 + 0] = __shfl(r.x, g2, 4);
    hk[g2 * 4 + 1] = __shfl(r.y, g2, 4);
    hk[g2 * 4 + 2] = __shfl(r.z, g2, 4);
    hk[g2 * 4 + 3] = __shfl(r.w, g2, 4);
  }
  int ob = g * 10;  // this lane's 10 output channels
  float lg[10];
#pragma unroll
  for (int t = 0; t < 10; ++t) lg[t] = lb[ob + t];
#pragma unroll
  for (int k = 0; k < 16; ++k) {
#pragma unroll
    for (int t = 0; t < 10; ++t) lg[t] = fmaf(hk[k], lw[k * 40 + ob + t], lg[t]);
  }
  float m = lg[0];
#pragma unroll
  for (int t = 1; t < 10; ++t) m = fmaxf(m, lg[t]);
  m = fmaxf(m, __shfl_xor(m, 1, 4));
  m = fmaxf(m, __shfl_xor(m, 2, 4));
  float se = 0.f;
#pragma unroll
  for (int t = 0; t < 10; ++t) se += __expf(lg[t] - m);
  se += __shfl_xor(se, 1, 4);
  se += __shfl_xor(se, 2, 4);
  float ls = __logf(se) + m;
#pragma unroll
  for (int t = 0; t < 10; ++t) out[(size_t)v * 40 + ob + t] = lg[t] - ls;
}

// ---------------- launcher ----------------
extern "C" void kernel_launch(void* const* d_in, const int* in_sizes, int n_in,
                              void* d_out, int out_size, void* d_ws, size_t ws_size,
                              hipStream_t stream) {
  (void)in_sizes; (void)n_in; (void)out_size; (void)ws_size;
  const float* x    = (const float*)d_in[0];
  const void*  ei   = d_in[1];
  const float* W1   = (const float*)d_in[2];
  const float* b1   = (const float*)d_in[3];
  const float* W2   = (const float*)d_in[4];
  const float* b2   = (const float*)d_in[5];
  const float* wihf = (const float*)d_in[6];
  const float* whhf = (const float*)d_in[7];
  const float* bfp  = (const float*)d_in[8];
  const float* wihb = (const float*)d_in[9];
  const float* whhb = (const float*)d_in[10];
  const float* bbp  = (const float*)d_in[11];
  const float* attw = (const float*)d_in[12];
  // d_in[13] = att_b: cancels exactly in the 2-way softmax -> unused
  const float* linw = (const float*)d_in[14];
  const float* linb = (const float*)d_in[15];
  float* out = (float*)d_out;

  char* w = (char*)d_ws;
  size_t off = 0;
  auto alloc = [&](size_t bytes) -> void* {
    void* p = w + off;
    off += (bytes + 255) & ~(size_t)255;
    return p;
  };
  int*   cnt    = (int*)alloc((size_t)NNODES * 4);
  float* dinv   = (float*)alloc((size_t)NNODES * 4);
  int*   rowoff = (int*)alloc((size_t)(NNODES + 1) * 4);
  int*   cursor = (int*)alloc((size_t)NNODES * 4);
  int*   bsum   = (int*)alloc(256 * 4);
  int*   boff   = (int*)alloc(256 * 4);
  int*   incb   = (int*)alloc((size_t)NNODES * 4);
  int*   flag   = (int*)alloc(256);
  int*   colv   = (int*)alloc((size_t)NEDGES * 4);
  float* bufA   = (float*)alloc((size_t)NNODES * 16 * 4);  // h0' / x2
  float* bufB   = (float*)alloc((size_t)NNODES * 16 * 4);  // x1
  float* bufC   = (float*)alloc((size_t)NNODES * 16 * 4);  // t2' / hjk'

  const int TPB = 256;
  const int gN  = (NNODES + TPB - 1) / TPB;        // 391
  const int gE  = (NEDGES + TPB - 1) / TPB;        // 12500
  const int nb1 = (NNODES + 1023) / 1024;          // 98
  const int gA  = (NNODES * 4 + TPB - 1) / TPB;    // 1563

  k_init<<<gN, TPB, 0, stream>>>((const unsigned int*)ei, cnt, flag, NNODES);
  k_count<<<gE, TPB, 0, stream>>>(ei, flag, cnt, NEDGES);
  k_scan1<<<nb1, 256, 0, stream>>>(cnt, incb, bsum, dinv, NNODES);
  k_scan2<<<1, 128, 0, stream>>>(bsum, boff, nb1);
  k_scan3<<<gN, TPB, 0, stream>>>(incb, boff, rowoff, cursor, NNODES);
  k_fill<<<gE, TPB, 0, stream>>>(ei, flag, cursor, colv, NEDGES);

  k_gemm1<<<1024, 256, 0, stream>>>(x, W1, dinv, bufA, NNODES);
  k_agg1<<<gA, TPB, 0, stream>>>(bufA, rowoff, colv, dinv, b1, W2, bufB, bufC,
                                 NNODES);                       // x1, t2'
  k_agg2<<<gA, TPB, 0, stream>>>(bufC, rowoff, colv, dinv, b2, bufA, NNODES); // x2
  k_lstm<<<1024, 256, 0, stream>>>(bufB, bufA, wihf, whhf, bfp, wihb, whhb, bbp,
                                   attw, dinv, bufC, NNODES);   // hjk'
  k_agg_out<<<gA, TPB, 0, stream>>>(bufC, rowoff, colv, dinv, linw, linb, out,
                                    NNODES);
}